// Round 3
// baseline (142.812 us; speedup 1.0000x reference)
//
#include <hip/hip_runtime.h>
#include <math.h>

// Problem constants (match reference)
#define T36   36
#define NPOLE 161
#define K645  645   // 4*161 + 1 dictionary columns
#define KP    648   // padded row length (float4-aligned rows)
#define KH    37    // compressed dim: 36 (span of D^T) + 1 (ones direction)
#define NITER 40
#define GAMMA_C 0.05

// ---------------------------------------------------------------------------
// ws layout (floats from base):
//   Dif  [36][648] @ 0      (23328)  normalized dictionary, i-major, f32, padded
//   G36  [36][36]  @ 23328  (1296)   f32 Gram
//   d1   [36]      @ 24624  (36)     f32 row sums
//   Mf   [645][37] @ 24660  (23865)  collapsed map, k-major
// total ~195 KB
// ---------------------------------------------------------------------------

// K1: build normalized dictionary via one sincos + rotation recurrence (f64
// internal, f32 out). Di[i][k] = dic[i][k] / ||dic[:,k]||.
__global__ void k_build(const float* __restrict__ rr, const float* __restrict__ theta,
                        float* __restrict__ Dif) {
    int k = blockIdx.x * blockDim.x + threadIdx.x;
    if (k >= KP) return;
    if (k >= K645) {              // zero the float4 padding columns
#pragma unroll
        for (int i = 0; i < T36; ++i) Dif[i * KP + k] = 0.f;
        return;
    }
    if (k == 0) {                 // ones column, norm sqrt(36)=6
        const float inv = 1.0f / 6.0f;
#pragma unroll
        for (int i = 0; i < T36; ++i) Dif[i * KP] = inv;
        return;
    }
    int g = (k - 1) / NPOLE;      // 0: r^i c, 1: (-r)^i c, 2: r^i s, 3: (-r)^i s
    int p = (k - 1) % NPOLE;
    double r  = (double)rr[p];
    double th = (double)theta[p];
    bool alt     = (g == 1) || (g == 3);
    bool use_sin = (g >= 2);
    double sth, cth;
    sincos(th, &sth, &cth);       // ONE transcendental; rest is rotation recurrence
    double ci = 1.0, si = 0.0, rp = 1.0, ss = 0.0;
    double val[T36];
#pragma unroll
    for (int i = 0; i < T36; ++i) {
        double v = rp * (use_sin ? si : ci);
        if (alt && (i & 1)) v = -v;
        val[i] = v;
        ss += v * v;
        double cn = ci * cth - si * sth;
        double sn = si * cth + ci * sth;
        ci = cn; si = sn; rp *= r;
    }
    double gn = sqrt(ss);
    if (gn == 0.0) gn = 6.0;      // reference: G==0 -> sqrt(T)
    double inv = 1.0 / gn;
#pragma unroll
    for (int i = 0; i < T36; ++i) Dif[i * KP + k] = (float)(val[i] * inv);
}

// K2: G36[a][b] = sum_k Dif[a][k]*Dif[b][k]  (b==36 -> d1[a] = sum_k Dif[a][k])
// float4 over contiguous padded rows; one wave per dot.
__global__ __launch_bounds__(64) void k_gram(const float* __restrict__ Dif,
                                             float* __restrict__ G36,
                                             float* __restrict__ d1v) {
    int a = blockIdx.x;           // 0..35
    int b = blockIdx.y;           // 0..36
    int lane = threadIdx.x;       // one wave
    const float4* Da = (const float4*)(Dif + a * KP);   // KP*4B = 2592 = 162*16
    float4 acc4 = make_float4(0.f, 0.f, 0.f, 0.f);
    if (b < T36) {
        const float4* Db = (const float4*)(Dif + b * KP);
        for (int c = lane; c < KP / 4; c += 64) {
            float4 va = Da[c], vb = Db[c];
            acc4.x += va.x * vb.x; acc4.y += va.y * vb.y;
            acc4.z += va.z * vb.z; acc4.w += va.w * vb.w;
        }
    } else {
        for (int c = lane; c < KP / 4; c += 64) {
            float4 va = Da[c];
            acc4.x += va.x; acc4.y += va.y; acc4.z += va.z; acc4.w += va.w;
        }
    }
    float acc = (acc4.x + acc4.y) + (acc4.z + acc4.w);
#pragma unroll
    for (int off = 32; off > 0; off >>= 1) acc += __shfl_xor(acc, off);
    if (lane == 0) {
        if (b < T36) G36[a * T36 + b] = acc;
        else         d1v[a] = acc;
    }
}

// K3: one wave per compressed column t. Frobenius norm of G (broadcast), H rows
// in registers (f64), 40-step linear FISTA recurrence with register state and
// __shfl broadcast (no LDS, no barriers in the loop), then expand this column:
// Mf[k][t] = sum_s Dif[s][k]*x[s] + x[36].
__global__ __launch_bounds__(64) void k_solve(const float* __restrict__ Dif,
                                              const float* __restrict__ G36,
                                              const float* __restrict__ d1v,
                                              float* __restrict__ Mf) {
    int t = blockIdx.x;           // 0..36
    int lane = threadIdx.x;       // 64 = one wave
    // ||G||_F, f64 accumulation of f32 entries, broadcast via xor-reduce
    double s = 0.0;
    for (int i = lane; i < T36 * T36; i += 64) { double v = (double)G36[i]; s += v * v; }
#pragma unroll
    for (int off = 32; off > 0; off >>= 1) s += __shfl_xor(s, off);
    double L = sqrt(s);
    double linv = (L == 0.0) ? 0.0 : 1.0 / L;
    double lambd = GAMMA_C * linv;

    double Hreg[KH];
    double Eh = 0.0;
    if (lane < T36) {
#pragma unroll
        for (int q = 0; q < T36; ++q)
            Hreg[q] = ((lane == q) ? 1.0 : 0.0) - linv * (double)G36[lane * T36 + q];
        Hreg[T36] = -linv * (double)d1v[lane];
        Eh = (lane == t && t < T36) ? linv : 0.0;
    } else if (lane == T36) {     // ones-direction passthrough row
#pragma unroll
        for (int q = 0; q < KH; ++q) Hreg[q] = (q == T36) ? 1.0 : 0.0;
        Eh = (t == T36) ? -lambd : 0.0;
    } else {
#pragma unroll
        for (int q = 0; q < KH; ++q) Hreg[q] = 0.0;
    }
    double y = 0.0, xold = 0.0;
    double tcur = 1.0;
    for (int n = 0; n < NITER; ++n) {
        // momentum coefficient, bit-matching reference's float32 tts
        double tn = 0.5 * (1.0 + sqrt(1.0 + 4.0 * tcur * tcur));
        double tt = (double)(float)((tcur - 1.0) / tn);
        tcur = tn;
        double a0 = Eh, a1 = 0.0, a2 = 0.0, a3 = 0.0;   // 4 chains cut latency
#pragma unroll
        for (int q = 0; q < T36; q += 4) {
            a0 += Hreg[q]     * __shfl(y, q);
            a1 += Hreg[q + 1] * __shfl(y, q + 1);
            a2 += Hreg[q + 2] * __shfl(y, q + 2);
            a3 += Hreg[q + 3] * __shfl(y, q + 3);
        }
        a0 += Hreg[T36] * __shfl(y, T36);
        double acc = (a0 + a1) + (a2 + a3);              // x_new = H*y + E
        double ynew = (1.0 + tt) * acc - tt * xold;
        xold = acc;
        y = ynew;
    }
    __shared__ float xs[KH];
    if (lane < KH) xs[lane] = (float)xold;   // final x, this block's column
    __syncthreads();                          // single-wave block: cheap
    float xr[KH];
#pragma unroll
    for (int q = 0; q < KH; ++q) xr[q] = xs[q];
    for (int k = lane; k < K645; k += 64) {
        float acc = xr[T36];
#pragma unroll
        for (int q = 0; q < T36; ++q) acc += Dif[q * KP + k] * xr[q];
        Mf[k * KH + t] = acc;
    }
}

// K4: out[k][p] = sum_t Mf[k][t]*Y[t][p] + Mf[k][36]
__global__ __launch_bounds__(256) void k_out(const float* __restrict__ Y,
                                             const float* __restrict__ Mf,
                                             float* __restrict__ out, int P) {
    int p = blockIdx.x * 256 + threadIdx.x;
    if (p >= P) return;
    int k0 = blockIdx.y * 15;     // 43 chunks * 15 = 645
    float y[T36];
#pragma unroll
    for (int t = 0; t < T36; ++t) y[t] = Y[t * P + p];
    for (int kk = 0; kk < 15; ++kk) {
        int k = k0 + kk;
        const float* m = Mf + k * KH;   // uniform across block -> scalar loads
        float acc = m[T36];
#pragma unroll
        for (int t = 0; t < T36; ++t) acc = fmaf(m[t], y[t], acc);
        out[k * P + p] = acc;
    }
}

extern "C" void kernel_launch(void* const* d_in, const int* in_sizes, int n_in,
                              void* d_out, int out_size, void* d_ws, size_t ws_size,
                              hipStream_t stream) {
    const float* x     = (const float*)d_in[0];   // [1, 36, 8192]
    const float* rr    = (const float*)d_in[1];   // [161]
    const float* theta = (const float*)d_in[2];   // [161]
    float* out = (float*)d_out;                   // [1, 645, 8192]

    float* wsf = (float*)d_ws;                    // needs ~195 KB
    float* Dif = wsf;                             // 36*648 = 23328
    float* G36 = wsf + 23328;                     // 1296
    float* d1v = wsf + 24624;                     // 36
    float* Mf  = wsf + 24660;                     // 645*37 = 23865

    int P = in_sizes[0] / T36;                    // 8192

    k_build<<<dim3(3), dim3(256), 0, stream>>>(rr, theta, Dif);
    k_gram<<<dim3(T36, KH), dim3(64), 0, stream>>>(Dif, G36, d1v);
    k_solve<<<dim3(KH), dim3(64), 0, stream>>>(Dif, G36, d1v, Mf);
    k_out<<<dim3((P + 255) / 256, 43), dim3(256), 0, stream>>>(x, Mf, out, P);
}

// Round 4
// 112.484 us; speedup vs baseline: 1.2696x; 1.2696x over previous
//
#include <hip/hip_runtime.h>
#include <math.h>

// Problem constants (match reference)
#define T36   36
#define NPOLE 161
#define K645  645   // 4*161 + 1 dictionary columns
#define KP    648   // padded row length (float4-aligned rows)
#define KH    37    // compressed dim: 36 (span of D^T) + 1 (ones direction)
#define NITER 40
#define GAMMA_C 0.05

// ---------------------------------------------------------------------------
// ws layout (floats from base):
//   Dif  [36][648] @ 0      (23328)  normalized dictionary, i-major, f32, padded
//   G36  [36][36]  @ 23328  (1296)   f32 Gram (= D·D^T, small side)
//   d1   [36]      @ 24624  (36)     f32 row sums (D·1)
//   tts  [40]      @ 24660  (40)     f32 momentum coefficients
//   Mf   [645][37] @ 24700  (23865)  collapsed affine map, k-major
// total ~195 KB
// ---------------------------------------------------------------------------

// K1: build normalized dictionary via one sincos + rotation recurrence (f64
// internal, f32 out). Di[i][k] = dic[i][k] / ||dic[:,k]||. One spare thread
// computes the 40 momentum coefficients (data-independent serial chain) so
// k_solve's inner loop has no sqrt/div on its critical path.
__global__ void k_build(const float* __restrict__ rr, const float* __restrict__ theta,
                        float* __restrict__ Dif, float* __restrict__ tts) {
    int k = blockIdx.x * blockDim.x + threadIdx.x;
    if (k == KP) {                // momentum table, bit-matching reference f32 tts
        double tcur = 1.0;
        for (int n = 0; n < NITER; ++n) {
            double tn = 0.5 * (1.0 + sqrt(1.0 + 4.0 * tcur * tcur));
            tts[n] = (float)((tcur - 1.0) / tn);
            tcur = tn;
        }
        return;
    }
    if (k > KP) return;
    if (k >= K645) {              // zero the float4 padding columns
#pragma unroll
        for (int i = 0; i < T36; ++i) Dif[i * KP + k] = 0.f;
        return;
    }
    if (k == 0) {                 // ones column, norm sqrt(36)=6
        const float inv = 1.0f / 6.0f;
#pragma unroll
        for (int i = 0; i < T36; ++i) Dif[i * KP] = inv;
        return;
    }
    int g = (k - 1) / NPOLE;      // 0: r^i c, 1: (-r)^i c, 2: r^i s, 3: (-r)^i s
    int p = (k - 1) % NPOLE;
    double r  = (double)rr[p];
    double th = (double)theta[p];
    bool alt     = (g == 1) || (g == 3);
    bool use_sin = (g >= 2);
    double sth, cth;
    sincos(th, &sth, &cth);       // ONE transcendental; rest is rotation recurrence
    double ci = 1.0, si = 0.0, rp = 1.0, ss = 0.0;
    double val[T36];
#pragma unroll
    for (int i = 0; i < T36; ++i) {
        double v = rp * (use_sin ? si : ci);
        if (alt && (i & 1)) v = -v;
        val[i] = v;
        ss += v * v;
        double cn = ci * cth - si * sth;
        double sn = si * cth + ci * sth;
        ci = cn; si = sn; rp *= r;
    }
    double gn = sqrt(ss);
    if (gn == 0.0) gn = 6.0;      // reference: G==0 -> sqrt(T)
    double inv = 1.0 / gn;
#pragma unroll
    for (int i = 0; i < T36; ++i) Dif[i * KP + k] = (float)(val[i] * inv);
}

// K2: G36[a][b] = sum_k Dif[a][k]*Dif[b][k]  (b==36 -> d1[a] = sum_k Dif[a][k])
// float4 over contiguous padded rows; one wave per dot.
__global__ __launch_bounds__(64) void k_gram(const float* __restrict__ Dif,
                                             float* __restrict__ G36,
                                             float* __restrict__ d1v) {
    int a = blockIdx.x;           // 0..35
    int b = blockIdx.y;           // 0..36
    int lane = threadIdx.x;       // one wave
    const float4* Da = (const float4*)(Dif + a * KP);   // KP*4B = 2592 = 162*16
    float4 acc4 = make_float4(0.f, 0.f, 0.f, 0.f);
    if (b < T36) {
        const float4* Db = (const float4*)(Dif + b * KP);
        for (int c = lane; c < KP / 4; c += 64) {
            float4 va = Da[c], vb = Db[c];
            acc4.x += va.x * vb.x; acc4.y += va.y * vb.y;
            acc4.z += va.z * vb.z; acc4.w += va.w * vb.w;
        }
    } else {
        for (int c = lane; c < KP / 4; c += 64) {
            float4 va = Da[c];
            acc4.x += va.x; acc4.y += va.y; acc4.z += va.z; acc4.w += va.w;
        }
    }
    float acc = (acc4.x + acc4.y) + (acc4.z + acc4.w);
#pragma unroll
    for (int off = 32; off > 0; off >>= 1) acc += __shfl_xor(acc, off);
    if (lane == 0) {
        if (b < T36) G36[a * T36 + b] = acc;
        else         d1v[a] = acc;
    }
}

// K3: one wave per compressed column t. ||G||_F broadcast, H rows in REGISTERS
// (launch_bounds(64,1) -> 256-VGPR budget, no spill), 40-step linear FISTA
// recurrence with y broadcast through LDS (uniform reads, conflict-free),
// momentum coefficients from precomputed table. Then expand this column:
// Mf[k][t] = sum_s Dif[s][k]*x[s] + x[36].
__global__ __launch_bounds__(64, 1) void k_solve(const float* __restrict__ Dif,
                                                 const float* __restrict__ G36,
                                                 const float* __restrict__ d1v,
                                                 const float* __restrict__ tts,
                                                 float* __restrict__ Mf) {
    int t = blockIdx.x;           // 0..36
    int lane = threadIdx.x;       // 64 = one wave
    __shared__ double yl[KH];
    __shared__ float  tl[NITER];
    __shared__ float  xs[KH];
    if (lane < NITER) tl[lane] = tts[lane];
    // ||G||_F, f64 accumulation of f32 entries, broadcast via xor-reduce
    double s = 0.0;
    for (int i = lane; i < T36 * T36; i += 64) { double v = (double)G36[i]; s += v * v; }
#pragma unroll
    for (int off = 32; off > 0; off >>= 1) s += __shfl_xor(s, off);
    double L = sqrt(s);
    double linv = (L == 0.0) ? 0.0 : 1.0 / L;
    double lambd = GAMMA_C * linv;

    double Hreg[KH];
    double Eh = 0.0;
    if (lane < T36) {
#pragma unroll
        for (int q = 0; q < T36; ++q)
            Hreg[q] = ((lane == q) ? 1.0 : 0.0) - linv * (double)G36[lane * T36 + q];
        Hreg[T36] = -linv * (double)d1v[lane];
        Eh = (lane == t && t < T36) ? linv : 0.0;
    } else if (lane == T36) {     // ones-direction passthrough row
#pragma unroll
        for (int q = 0; q < KH; ++q) Hreg[q] = (q == T36) ? 1.0 : 0.0;
        Eh = (t == T36) ? -lambd : 0.0;
    } else {
#pragma unroll
        for (int q = 0; q < KH; ++q) Hreg[q] = 0.0;
    }
    if (lane < KH) yl[lane] = 0.0;
    __syncthreads();              // 1-wave block: s_barrier, ~free

    double xold = 0.0;
    for (int n = 0; n < NITER; ++n) {
        double tt = (double)tl[n];               // uniform LDS read, off chain
        double a0 = Eh, a1 = 0.0, a2 = 0.0, a3 = 0.0;
#pragma unroll
        for (int q = 0; q < T36; q += 4) {       // uniform broadcast reads of y
            a0 += Hreg[q]     * yl[q];
            a1 += Hreg[q + 1] * yl[q + 1];
            a2 += Hreg[q + 2] * yl[q + 2];
            a3 += Hreg[q + 3] * yl[q + 3];
        }
        a0 += Hreg[T36] * yl[T36];
        double acc = (a0 + a1) + (a2 + a3);      // x_new = H*y + E
        double ynew = (1.0 + tt) * acc - tt * xold;
        xold = acc;
        __syncthreads();                          // reads done before overwrite
        if (lane < KH) yl[lane] = ynew;
        __syncthreads();
    }
    if (lane < KH) xs[lane] = (float)xold;        // final x, this block's column
    __syncthreads();
    float xr[KH];
#pragma unroll
    for (int q = 0; q < KH; ++q) xr[q] = xs[q];
    for (int k = lane; k < K645; k += 64) {       // coalesced over k
        float acc = xr[T36];
#pragma unroll
        for (int q = 0; q < T36; ++q) acc += Dif[q * KP + k] * xr[q];
        Mf[k * KH + t] = acc;
    }
}

// K4: out[k][p] = sum_t Mf[k][t]*Y[t][p] + Mf[k][36]
__global__ __launch_bounds__(256) void k_out(const float* __restrict__ Y,
                                             const float* __restrict__ Mf,
                                             float* __restrict__ out, int P) {
    int p = blockIdx.x * 256 + threadIdx.x;
    if (p >= P) return;
    int k0 = blockIdx.y * 15;     // 43 chunks * 15 = 645
    float y[T36];
#pragma unroll
    for (int t = 0; t < T36; ++t) y[t] = Y[t * P + p];
    for (int kk = 0; kk < 15; ++kk) {
        int k = k0 + kk;
        const float* m = Mf + k * KH;   // uniform across block -> scalar loads
        float acc = m[T36];
#pragma unroll
        for (int t = 0; t < T36; ++t) acc = fmaf(m[t], y[t], acc);
        out[k * P + p] = acc;
    }
}

extern "C" void kernel_launch(void* const* d_in, const int* in_sizes, int n_in,
                              void* d_out, int out_size, void* d_ws, size_t ws_size,
                              hipStream_t stream) {
    const float* x     = (const float*)d_in[0];   // [1, 36, 8192]
    const float* rr    = (const float*)d_in[1];   // [161]
    const float* theta = (const float*)d_in[2];   // [161]
    float* out = (float*)d_out;                   // [1, 645, 8192]

    float* wsf = (float*)d_ws;                    // needs ~195 KB
    float* Dif = wsf;                             // 36*648 = 23328
    float* G36 = wsf + 23328;                     // 1296
    float* d1v = wsf + 24624;                     // 36
    float* tts = wsf + 24660;                     // 40
    float* Mf  = wsf + 24700;                     // 645*37 = 23865

    int P = in_sizes[0] / T36;                    // 8192

    k_build<<<dim3(3), dim3(256), 0, stream>>>(rr, theta, Dif, tts);
    k_gram<<<dim3(T36, KH), dim3(64), 0, stream>>>(Dif, G36, d1v);
    k_solve<<<dim3(KH), dim3(64), 0, stream>>>(Dif, G36, d1v, tts, Mf);
    k_out<<<dim3((P + 255) / 256, 43), dim3(256), 0, stream>>>(x, Mf, out, P);
}

// Round 5
// 109.930 us; speedup vs baseline: 1.2991x; 1.0232x over previous
//
#include <hip/hip_runtime.h>
#include <math.h>

// Problem constants (match reference)
#define T36   36
#define NPOLE 161
#define K645  645   // 4*161 + 1 dictionary columns
#define KP    648   // padded row length (float4-aligned rows)
#define KH    37    // compressed dim: 36 (span of D^T) + 1 (ones direction)
#define NITER 40
#define GAMMA_C 0.05

// ---------------------------------------------------------------------------
// ws layout (floats from base):
//   Dif  [36][648] @ 0      (23328)  normalized dictionary, i-major, f32, padded
//   G36  [36][36]  @ 23328  (1296)   f32 Gram (= D·D^T, small side)
//   d1   [36]      @ 24624  (36)     f32 row sums (D·1)
//   tts  [40]      @ 24660  (40)     f32 momentum coefficients
//   Mf   [645][37] @ 24700  (23865)  collapsed affine map, k-major
// total ~195 KB
// ---------------------------------------------------------------------------

// K1: build normalized dictionary via one sincos + rotation recurrence (f64
// internal, f32 out). Di[i][k] = dic[i][k] / ||dic[:,k]||. One spare thread
// computes the 40 momentum coefficients (data-independent serial chain) so
// k_solve's inner loop has no sqrt/div on its critical path.
__global__ void k_build(const float* __restrict__ rr, const float* __restrict__ theta,
                        float* __restrict__ Dif, float* __restrict__ tts) {
    int k = blockIdx.x * blockDim.x + threadIdx.x;
    if (k == KP) {                // momentum table, bit-matching reference f32 tts
        double tcur = 1.0;
        for (int n = 0; n < NITER; ++n) {
            double tn = 0.5 * (1.0 + sqrt(1.0 + 4.0 * tcur * tcur));
            tts[n] = (float)((tcur - 1.0) / tn);
            tcur = tn;
        }
        return;
    }
    if (k > KP) return;
    if (k >= K645) {              // zero the float4 padding columns
#pragma unroll
        for (int i = 0; i < T36; ++i) Dif[i * KP + k] = 0.f;
        return;
    }
    if (k == 0) {                 // ones column, norm sqrt(36)=6
        const float inv = 1.0f / 6.0f;
#pragma unroll
        for (int i = 0; i < T36; ++i) Dif[i * KP] = inv;
        return;
    }
    int g = (k - 1) / NPOLE;      // 0: r^i c, 1: (-r)^i c, 2: r^i s, 3: (-r)^i s
    int p = (k - 1) % NPOLE;
    double r  = (double)rr[p];
    double th = (double)theta[p];
    bool alt     = (g == 1) || (g == 3);
    bool use_sin = (g >= 2);
    double sth, cth;
    sincos(th, &sth, &cth);       // ONE transcendental; rest is rotation recurrence
    double ci = 1.0, si = 0.0, rp = 1.0, ss = 0.0;
    double val[T36];
#pragma unroll
    for (int i = 0; i < T36; ++i) {
        double v = rp * (use_sin ? si : ci);
        if (alt && (i & 1)) v = -v;
        val[i] = v;
        ss += v * v;
        double cn = ci * cth - si * sth;
        double sn = si * cth + ci * sth;
        ci = cn; si = sn; rp *= r;
    }
    double gn = sqrt(ss);
    if (gn == 0.0) gn = 6.0;      // reference: G==0 -> sqrt(T)
    double inv = 1.0 / gn;
#pragma unroll
    for (int i = 0; i < T36; ++i) Dif[i * KP + k] = (float)(val[i] * inv);
}

// K2: G36[a][b] = sum_k Dif[a][k]*Dif[b][k]; symmetric -> compute b>=a only,
// write both. b==36 computes d1[a] = sum_k Dif[a][k]. float4 coalesced rows.
__global__ __launch_bounds__(64) void k_gram(const float* __restrict__ Dif,
                                             float* __restrict__ G36,
                                             float* __restrict__ d1v) {
    int a = blockIdx.x;           // 0..35
    int b = blockIdx.y;           // 0..36
    if (b < a) return;            // symmetry: lower triangle handled by mirror write
    int lane = threadIdx.x;       // one wave
    const float4* Da = (const float4*)(Dif + a * KP);   // KP*4B = 2592 = 162*16
    float4 acc4 = make_float4(0.f, 0.f, 0.f, 0.f);
    if (b < T36) {
        const float4* Db = (const float4*)(Dif + b * KP);
        for (int c = lane; c < KP / 4; c += 64) {
            float4 va = Da[c], vb = Db[c];
            acc4.x += va.x * vb.x; acc4.y += va.y * vb.y;
            acc4.z += va.z * vb.z; acc4.w += va.w * vb.w;
        }
    } else {
        for (int c = lane; c < KP / 4; c += 64) {
            float4 va = Da[c];
            acc4.x += va.x; acc4.y += va.y; acc4.z += va.z; acc4.w += va.w;
        }
    }
    float acc = (acc4.x + acc4.y) + (acc4.z + acc4.w);
#pragma unroll
    for (int off = 32; off > 0; off >>= 1) acc += __shfl_xor(acc, off);
    if (lane == 0) {
        if (b < T36) { G36[a * T36 + b] = acc; G36[b * T36 + a] = acc; }
        else         d1v[a] = acc;
    }
}

// K3: one wave per compressed column t. ||G||_F broadcast, H rows in registers
// (launch_bounds(64,1) -> full VGPR budget, no spill), 40-step linear FISTA
// recurrence. y-state lives in LDS as double2 (uniform ds_read_b128, 19 reads
// per iter instead of 37) and is DOUBLE-BUFFERED -> one barrier per iteration.
// Then expand this column: Mf[k][t] = sum_s Dif[s][k]*x[s] + x[36].
__global__ __launch_bounds__(64, 1) void k_solve(const float* __restrict__ Dif,
                                                 const float* __restrict__ G36,
                                                 const float* __restrict__ d1v,
                                                 const float* __restrict__ tts,
                                                 float* __restrict__ Mf) {
    int t = blockIdx.x;           // 0..36
    int lane = threadIdx.x;       // 64 = one wave
    __shared__ double2 yl2[2][19];                 // 19 pairs = 38 doubles (37 used)
    __shared__ float  tl[NITER];
    __shared__ float  xs[KH];
    if (lane < NITER) tl[lane] = tts[lane];
    // ||G||_F, f64 accumulation of f32 entries, broadcast via xor-reduce
    double s = 0.0;
    for (int i = lane; i < T36 * T36; i += 64) { double v = (double)G36[i]; s += v * v; }
#pragma unroll
    for (int off = 32; off > 0; off >>= 1) s += __shfl_xor(s, off);
    double L = sqrt(s);
    double linv = (L == 0.0) ? 0.0 : 1.0 / L;
    double lambd = GAMMA_C * linv;

    double Hreg[KH];
    double Eh = 0.0;
    if (lane < T36) {
#pragma unroll
        for (int q = 0; q < T36; ++q)
            Hreg[q] = ((lane == q) ? 1.0 : 0.0) - linv * (double)G36[lane * T36 + q];
        Hreg[T36] = -linv * (double)d1v[lane];
        Eh = (lane == t && t < T36) ? linv : 0.0;
    } else if (lane == T36) {     // ones-direction passthrough row
#pragma unroll
        for (int q = 0; q < KH; ++q) Hreg[q] = (q == T36) ? 1.0 : 0.0;
        Eh = (t == T36) ? -lambd : 0.0;
    } else {
#pragma unroll
        for (int q = 0; q < KH; ++q) Hreg[q] = 0.0;
    }
    if (lane < 38) {              // zero both y buffers (element 37 is padding)
        ((double*)yl2[0])[lane] = 0.0;
        ((double*)yl2[1])[lane] = 0.0;
    }
    __syncthreads();

    double xold = 0.0;
    for (int n = 0; n < NITER; ++n) {
        const double2* y = yl2[n & 1];
        double tt = (double)tl[n];               // uniform LDS read, off chain
        double a0 = Eh, a1 = 0.0, a2 = 0.0, a3 = 0.0;
#pragma unroll
        for (int j = 0; j < 18; j += 2) {        // 18 pairs cover q=0..35
            double2 p0 = y[j];                   // uniform ds_read_b128
            double2 p1 = y[j + 1];
            a0 += Hreg[2 * j]     * p0.x;
            a1 += Hreg[2 * j + 1] * p0.y;
            a2 += Hreg[2 * j + 2] * p1.x;
            a3 += Hreg[2 * j + 3] * p1.y;
        }
        a0 += Hreg[T36] * y[18].x;               // q = 36
        double acc = (a0 + a1) + (a2 + a3);      // x_new = H*y + E
        double ynew = (1.0 + tt) * acc - tt * xold;
        xold = acc;
        if (lane < KH) ((double*)yl2[(n + 1) & 1])[lane] = ynew;
        __syncthreads();                          // write visible before next read
    }
    if (lane < KH) xs[lane] = (float)xold;        // final x, this block's column
    __syncthreads();
    float xr[KH];
#pragma unroll
    for (int q = 0; q < KH; ++q) xr[q] = xs[q];
    for (int k = lane; k < K645; k += 64) {       // coalesced over k
        float acc = xr[T36];
#pragma unroll
        for (int q = 0; q < T36; ++q) acc += Dif[q * KP + k] * xr[q];
        Mf[k * KH + t] = acc;
    }
}

// K4: out[k][p] = sum_t Mf[k][t]*Y[t][p] + Mf[k][36]. float2 per thread:
// 8 B/lane loads + stores (coalescing sweet spot), half the memory instrs.
__global__ __launch_bounds__(256) void k_out(const float* __restrict__ Y,
                                             const float* __restrict__ Mf,
                                             float* __restrict__ out, int P) {
    int P2 = P >> 1;
    int p2 = blockIdx.x * 256 + threadIdx.x;      // float2 index
    if (p2 >= P2) return;
    int k0 = blockIdx.y * 15;     // 43 chunks * 15 = 645
    const float2* Y2 = (const float2*)Y;
    float2* out2 = (float2*)out;
    float2 y[T36];
#pragma unroll
    for (int t = 0; t < T36; ++t) y[t] = Y2[t * P2 + p2];
    for (int kk = 0; kk < 15; ++kk) {
        int k = k0 + kk;
        const float* m = Mf + k * KH;   // uniform across block -> scalar loads
        float ax = m[T36], ay = m[T36];
#pragma unroll
        for (int t = 0; t < T36; ++t) {
            float c = m[t];
            ax = fmaf(c, y[t].x, ax);
            ay = fmaf(c, y[t].y, ay);
        }
        out2[k * P2 + p2] = make_float2(ax, ay);
    }
}

extern "C" void kernel_launch(void* const* d_in, const int* in_sizes, int n_in,
                              void* d_out, int out_size, void* d_ws, size_t ws_size,
                              hipStream_t stream) {
    const float* x     = (const float*)d_in[0];   // [1, 36, 8192]
    const float* rr    = (const float*)d_in[1];   // [161]
    const float* theta = (const float*)d_in[2];   // [161]
    float* out = (float*)d_out;                   // [1, 645, 8192]

    float* wsf = (float*)d_ws;                    // needs ~195 KB
    float* Dif = wsf;                             // 36*648 = 23328
    float* G36 = wsf + 23328;                     // 1296
    float* d1v = wsf + 24624;                     // 36
    float* tts = wsf + 24660;                     // 40
    float* Mf  = wsf + 24700;                     // 645*37 = 23865

    int P = in_sizes[0] / T36;                    // 8192

    k_build<<<dim3(3), dim3(256), 0, stream>>>(rr, theta, Dif, tts);
    k_gram<<<dim3(T36, KH), dim3(64), 0, stream>>>(Dif, G36, d1v);
    k_solve<<<dim3(KH), dim3(64), 0, stream>>>(Dif, G36, d1v, tts, Mf);
    k_out<<<dim3((P / 2 + 255) / 256, 43), dim3(256), 0, stream>>>(x, Mf, out, P);
}